// Round 7
// baseline (427.545 us; speedup 1.0000x reference)
//
#include <hip/hip_runtime.h>
#include <hip/hip_fp16.h>
#include <cstdint>

// Shapes (hard-coded): B=4, Cx=512, Cy=256, M=64, H=W=64, N=4096
constexpr int N_ = 4096;
constexpr float CNT = 16384.f;  // B*N reduction count for BN stats
constexpr float LOG2E = 1.4426950408889634f;

typedef __attribute__((ext_vector_type(8))) _Float16 half8;
typedef __attribute__((ext_vector_type(4))) float f32x4;
union fragh { half8 h8; int i4[4]; int4 v4; };

__device__ inline int pkh(float a, float b) {
  union { __half2 h; int i; } u;
  u.h = __float22half2_rn(float2{a, b});
  return u.i;
}

// Stats layout (floats): group g in {0:s1,1:x1,2:y1,3:s2,4:x2,5:y2}:
//   sum at g*128+c, sumsq at g*128+64+c (c<64). f_up: sum 768+c, sumsq 1280+c.

// ---------------- stage-1 convs: SGEMM tiling (validated round 6) ------------------
__global__ __launch_bounds__(256) void conv1_k(
    const float* __restrict__ x, const float* __restrict__ y,
    const float* __restrict__ ws1, const float* __restrict__ wx1,
    const float* __restrict__ wy1,
    float* __restrict__ z1s, float* __restrict__ z1x, float* __restrict__ z1y,
    float* __restrict__ stats) {
  const int t = threadIdx.x;
  const int slice = blockIdx.x;  // 0..127
  const int b = slice >> 5;
  const int n0 = (slice & 31) * 128;
  const int branch = blockIdx.y;  // 0:s 1:x 2:y
  const float* A = branch == 2 ? y : x;
  const float* W = branch == 0 ? ws1 : (branch == 1 ? wx1 : wy1);
  float* out = branch == 0 ? z1s : (branch == 1 ? z1x : z1y);
  const int K = branch == 2 ? 256 : 512;
  float* st = stats + branch * 128;

  __shared__ float sA[32][132];
  __shared__ float sW[32][72];

  const int to = (t >> 5) * 8;
  const int tn = (t & 31) * 4;
  float acc[8][4];
#pragma unroll
  for (int i = 0; i < 8; ++i)
#pragma unroll
    for (int j = 0; j < 4; ++j) acc[i][j] = 0.f;

  const float* Ab = A + (size_t)b * K * N_ + n0;
#pragma unroll 1
  for (int k0 = 0; k0 < K; k0 += 32) {
    __syncthreads();
#pragma unroll
    for (int i = 0; i < 4; ++i) {
      int row = i * 8 + (t >> 5);
      float4 v = *(const float4*)&Ab[(size_t)(k0 + row) * N_ + tn];
      *(float4*)&sA[row][tn] = v;
    }
    {
      int o = t >> 2, kk = (t & 3) * 8;
      float4 w0 = *(const float4*)&W[(size_t)o * K + k0 + kk];
      float4 w1 = *(const float4*)&W[(size_t)o * K + k0 + kk + 4];
      sW[kk + 0][o] = w0.x; sW[kk + 1][o] = w0.y;
      sW[kk + 2][o] = w0.z; sW[kk + 3][o] = w0.w;
      sW[kk + 4][o] = w1.x; sW[kk + 5][o] = w1.y;
      sW[kk + 6][o] = w1.z; sW[kk + 7][o] = w1.w;
    }
    __syncthreads();
#pragma unroll
    for (int k = 0; k < 32; ++k) {
      float4 a = *(const float4*)&sA[k][tn];
      float4 w0 = *(const float4*)&sW[k][to];
      float4 w1 = *(const float4*)&sW[k][to + 4];
      float wv[8] = {w0.x, w0.y, w0.z, w0.w, w1.x, w1.y, w1.z, w1.w};
      float av[4] = {a.x, a.y, a.z, a.w};
#pragma unroll
      for (int i = 0; i < 8; ++i)
#pragma unroll
        for (int j = 0; j < 4; ++j) acc[i][j] += wv[i] * av[j];
    }
  }
  float* Cb = out + (size_t)b * 64 * N_ + n0;
#pragma unroll
  for (int i = 0; i < 8; ++i) {
    float4 v = {acc[i][0], acc[i][1], acc[i][2], acc[i][3]};
    *(float4*)&Cb[(size_t)(to + i) * N_ + tn] = v;
  }
#pragma unroll
  for (int i = 0; i < 8; ++i) {
    float s = acc[i][0] + acc[i][1] + acc[i][2] + acc[i][3];
    float q = acc[i][0] * acc[i][0] + acc[i][1] * acc[i][1] +
              acc[i][2] * acc[i][2] + acc[i][3] * acc[i][3];
#pragma unroll
    for (int d = 1; d < 32; d <<= 1) { s += __shfl_xor(s, d); q += __shfl_xor(q, d); }
    if ((t & 31) == 0) { atomicAdd(&st[to + i], s); atomicAdd(&st[64 + to + i], q); }
  }
}

// ---------------- stage-2 convs (K=64), BN1 applied during A staging ---------------
__global__ __launch_bounds__(256) void conv2_k(
    const float* __restrict__ z1s, const float* __restrict__ z1x,
    const float* __restrict__ z1y,
    const float* __restrict__ ws2, const float* __restrict__ wx2,
    const float* __restrict__ wy2,
    const float* __restrict__ gs1, const float* __restrict__ bs1,
    const float* __restrict__ gx1, const float* __restrict__ bx1,
    const float* __restrict__ gy1, const float* __restrict__ by1,
    float* __restrict__ z2s, float* __restrict__ z2x, float* __restrict__ z2y,
    float* __restrict__ stats) {
  const int t = threadIdx.x;
  const int slice = blockIdx.x;
  const int b = slice >> 5;
  const int n0 = (slice & 31) * 128;
  const int branch = blockIdx.y;
  const float* A = branch == 0 ? z1s : (branch == 1 ? z1x : z1y);
  const float* W = branch == 0 ? ws2 : (branch == 1 ? wx2 : wy2);
  const float* g1 = branch == 0 ? gs1 : (branch == 1 ? gx1 : gy1);
  const float* b1 = branch == 0 ? bs1 : (branch == 1 ? bx1 : by1);
  float* out = branch == 0 ? z2s : (branch == 1 ? z2x : z2y);
  const float* stin = stats + branch * 128;
  float* stout = stats + (3 + branch) * 128;

  __shared__ float sA[32][132];
  __shared__ float sW[32][72];
  __shared__ float sc[64], sh[64];

  if (t < 64) {
    float mean = stin[t] * (1.f / CNT);
    float var = stin[64 + t] * (1.f / CNT) - mean * mean;
    float r = rsqrtf(var + 1e-5f);
    float s = g1[t] * r;
    sc[t] = s;
    sh[t] = b1[t] - mean * s;
  }

  const int to = (t >> 5) * 8;
  const int tn = (t & 31) * 4;
  float acc[8][4];
#pragma unroll
  for (int i = 0; i < 8; ++i)
#pragma unroll
    for (int j = 0; j < 4; ++j) acc[i][j] = 0.f;

  const float* Ab = A + (size_t)b * 64 * N_ + n0;
#pragma unroll 1
  for (int k0 = 0; k0 < 64; k0 += 32) {
    __syncthreads();
#pragma unroll
    for (int i = 0; i < 4; ++i) {
      int row = i * 8 + (t >> 5);
      float4 v = *(const float4*)&Ab[(size_t)(k0 + row) * N_ + tn];
      float s = sc[k0 + row], h = sh[k0 + row];
      v.x = v.x * s + h; v.y = v.y * s + h; v.z = v.z * s + h; v.w = v.w * s + h;
      *(float4*)&sA[row][tn] = v;
    }
    {
      int o = t >> 2, kk = (t & 3) * 8;
      float4 w0 = *(const float4*)&W[(size_t)o * 64 + k0 + kk];
      float4 w1 = *(const float4*)&W[(size_t)o * 64 + k0 + kk + 4];
      sW[kk + 0][o] = w0.x; sW[kk + 1][o] = w0.y;
      sW[kk + 2][o] = w0.z; sW[kk + 3][o] = w0.w;
      sW[kk + 4][o] = w1.x; sW[kk + 5][o] = w1.y;
      sW[kk + 6][o] = w1.z; sW[kk + 7][o] = w1.w;
    }
    __syncthreads();
#pragma unroll
    for (int k = 0; k < 32; ++k) {
      float4 a = *(const float4*)&sA[k][tn];
      float4 w0 = *(const float4*)&sW[k][to];
      float4 w1 = *(const float4*)&sW[k][to + 4];
      float wv[8] = {w0.x, w0.y, w0.z, w0.w, w1.x, w1.y, w1.z, w1.w};
      float av[4] = {a.x, a.y, a.z, a.w};
#pragma unroll
      for (int i = 0; i < 8; ++i)
#pragma unroll
        for (int j = 0; j < 4; ++j) acc[i][j] += wv[i] * av[j];
    }
  }
  float* Cb = out + (size_t)b * 64 * N_ + n0;
#pragma unroll
  for (int i = 0; i < 8; ++i) {
    float4 v = {acc[i][0], acc[i][1], acc[i][2], acc[i][3]};
    *(float4*)&Cb[(size_t)(to + i) * N_ + tn] = v;
  }
#pragma unroll
  for (int i = 0; i < 8; ++i) {
    float s = acc[i][0] + acc[i][1] + acc[i][2] + acc[i][3];
    float q = acc[i][0] * acc[i][0] + acc[i][1] * acc[i][1] +
              acc[i][2] * acc[i][2] + acc[i][3] * acc[i][3];
#pragma unroll
    for (int d = 1; d < 32; d <<= 1) { s += __shfl_xor(s, d); q += __shfl_xor(q, d); }
    if ((t & 31) == 0) { atomicAdd(&stout[to + i], s); atomicAdd(&stout[64 + to + i], q); }
  }
}

// ---------------- pack Q: [b][c-pair 0..31][n], values scaled by log2(e) -----------
__global__ __launch_bounds__(256) void packQ_k(const float* __restrict__ z2x,
                                               const float* __restrict__ gx2,
                                               const float* __restrict__ bx2,
                                               int* __restrict__ Qh,
                                               const float* __restrict__ stats) {
  const int idx = blockIdx.x * 256 + threadIdx.x;  // 0..524287
  const float* st = stats + 4 * 128;
  int n = idx & 4095, c = (idx >> 12) & 31, b = idx >> 17;
  auto snorm = [&](int ch, float& s, float& h) {
    float mean = st[ch] * (1.f / CNT);
    float var = st[64 + ch] * (1.f / CNT) - mean * mean;
    float r = rsqrtf(var + 1e-5f);
    s = gx2[ch] * r * LOG2E;
    h = (bx2[ch] - mean * gx2[ch] * r) * LOG2E;
  };
  float s0, h0, s1, h1;
  snorm(2 * c, s0, h0);
  snorm(2 * c + 1, s1, h1);
  float v0 = z2x[((size_t)b * 64 + 2 * c) * N_ + n] * s0 + h0;
  float v1 = z2x[((size_t)b * 64 + 2 * c + 1) * N_ + n] * s1 + h1;
  Qh[idx] = pkh(v0, v1);
}

// ---------------- pack K: transpose to [b][key][c-pair 0..31] ----------------------
__global__ __launch_bounds__(256) void packK_k(const float* __restrict__ z2y,
                                               const float* __restrict__ gy2,
                                               const float* __restrict__ by2,
                                               int* __restrict__ Kh,
                                               const float* __restrict__ stats) {
  const int t = threadIdx.x;
  const int key0 = blockIdx.x * 64;
  const int b = blockIdx.y;
  const float* st = stats + 5 * 128;
  __shared__ float tile[64][68];
  __shared__ float sc[64], sh[64];
  if (t < 64) {
    float mean = st[t] * (1.f / CNT);
    float var = st[64 + t] * (1.f / CNT) - mean * mean;
    float r = rsqrtf(var + 1e-5f);
    float s = gy2[t] * r;
    sc[t] = s;
    sh[t] = by2[t] - mean * s;
  }
  __syncthreads();
#pragma unroll
  for (int it = 0; it < 4; ++it) {
    int lin = it * 256 + t;     // 1024 float4 slots: ch = lin>>4, f4i = lin&15
    int ch = lin >> 4, f4i = lin & 15;
    float4 v = *(const float4*)&z2y[((size_t)b * 64 + ch) * N_ + key0 + f4i * 4];
    float s = sc[ch], h = sh[ch];
    v.x = v.x * s + h; v.y = v.y * s + h; v.z = v.z * s + h; v.w = v.w * s + h;
    *(float4*)&tile[ch][f4i * 4] = v;
  }
  __syncthreads();
  const int key = t >> 2, cg = t & 3;
  int outv[8];
#pragma unroll
  for (int i = 0; i < 8; ++i) {
    int c = cg * 8 + i;
    outv[i] = pkh(tile[2 * c][key], tile[2 * c + 1][key]);
  }
  int* dst = Kh + ((size_t)b * N_ + key0 + key) * 32 + cg * 8;
  *(int4*)dst = *(int4*)&outv[0];
  *(int4*)(dst + 4) = *(int4*)&outv[4];
}

// ---------------- pack V: [b][pair-block 0..127][feature 0..63][pair 0..15] --------
__global__ __launch_bounds__(256) void packV_k(const float* __restrict__ z2s,
                                               const float* __restrict__ gs2,
                                               const float* __restrict__ bs2,
                                               int* __restrict__ Vp,
                                               const float* __restrict__ stats) {
  const int idx = blockIdx.x * 256 + threadIdx.x;  // 0..524287
  const float* st = stats + 3 * 128;
  int pil = idx & 15, ch = (idx >> 4) & 63, pb = (idx >> 10) & 127, b = idx >> 17;
  float mean = st[ch] * (1.f / CNT);
  float var = st[64 + ch] * (1.f / CNT) - mean * mean;
  float r = rsqrtf(var + 1e-5f);
  float s = gs2[ch] * r;
  float h = bs2[ch] - mean * s;
  float2 v = *(const float2*)&z2s[((size_t)b * 64 + ch) * N_ + pb * 32 + pil * 2];
  Vp[idx] = pkh(v.x * s + h, v.y * s + h);
}

// ---------------- MFMA fp16 flash attention, transpose-free S^T design -------------
// S^T = mfma(A=K, B=Q): C col=query(la), row=key. Permuted key map
// key_in_tile = (m&3)+nt*4+(m>>2)*8 makes each lane's 8 p-values exactly its PV
// B-frag slot k=quad*8+j -> P packs straight to B-operand, zero LDS in K-loop.
// Softmax in exp2 domain (log2e folded into Q at pack). Block = 4 waves split-K.
__global__ __launch_bounds__(256, 4) void attn_k(const int* __restrict__ Qh,
                                                 const int* __restrict__ Kh,
                                                 const int* __restrict__ Vp,
                                                 float* __restrict__ fout) {
  const int tid = threadIdx.x;
  const int lane = tid & 63;
  const int wid = tid >> 6;
  const int la = lane & 15;
  const int quad = lane >> 4;
  const int b = blockIdx.x & 3;
  const int qbase = (blockIdx.x >> 2) * 16;
  const int* Qb = Qh + (size_t)b * 32 * N_;
  const int* Kb = Kh + (size_t)b * 32 * N_;
  const int* Vb = Vp + (size_t)b * 128 * 1024;

  __shared__ struct { float O[4][16][68]; float M[4][16]; float L[4][16]; } sm;

  // Q B-frag: B[k=ch quad*8+j][n=q la]
  fragh qb[2];
#pragma unroll
  for (int h = 0; h < 2; ++h)
#pragma unroll
    for (int jj = 0; jj < 4; ++jj)
      qb[h].i4[jj] = Qb[(size_t)(h * 16 + quad * 4 + jj) * N_ + qbase + la];

  const int keyrow = (la & 3) + ((la >> 2) << 3);  // permuted key row for A m=la

  f32x4 o[4];
#pragma unroll
  for (int mt = 0; mt < 4; ++mt) o[mt] = f32x4{0.f, 0.f, 0.f, 0.f};
  float mrun = -3.0e38f, lrun = 0.f;

  const int jbeg = wid * 1024;
  const int* kptr = Kb + (jbeg + keyrow) * 32 + quad * 4;
  const int* vptr = Vb + (jbeg >> 5) * 1024 + la * 16 + quad * 4;
#pragma unroll 1
  for (int it = 0; it < 32; ++it) {
    // K A-frags: 4 dwordx4 at immediate offsets
    fragh ka[2][2];
#pragma unroll
    for (int nt = 0; nt < 2; ++nt)
#pragma unroll
      for (int h = 0; h < 2; ++h)
        ka[nt][h].v4 = *(const int4*)(kptr + nt * 128 + h * 16);
    // V A-frags: 4 dwordx4
    fragh va[4];
#pragma unroll
    for (int mt = 0; mt < 4; ++mt) va[mt].v4 = *(const int4*)(vptr + mt * 256);
    kptr += 1024;
    vptr += 1024;
    // QK^T -> S^T (col=q la, row=key)
    f32x4 s[2];
#pragma unroll
    for (int nt = 0; nt < 2; ++nt) {
      f32x4 z = f32x4{0.f, 0.f, 0.f, 0.f};
      z = __builtin_amdgcn_mfma_f32_16x16x32_f16(ka[nt][0].h8, qb[0].h8, z, 0, 0, 0);
      s[nt] = __builtin_amdgcn_mfma_f32_16x16x32_f16(ka[nt][1].h8, qb[1].h8, z, 0, 0, 0);
    }
    // softmax over this lane's 8 keys + cross-quad combine (2 shuffles total)
    float t0 = fmaxf(fmaxf(s[0][0], s[0][1]), fmaxf(s[0][2], s[0][3]));
    float t1 = fmaxf(fmaxf(s[1][0], s[1][1]), fmaxf(s[1][2], s[1][3]));
    float t = fmaxf(t0, t1);
    t = fmaxf(t, __shfl_xor(t, 16));
    t = fmaxf(t, __shfl_xor(t, 32));
    float mnew = fmaxf(mrun, t);
    float alpha = exp2f(mrun - mnew);
    float p[2][4];
    float ps = 0.f;
#pragma unroll
    for (int nt = 0; nt < 2; ++nt)
#pragma unroll
      for (int r = 0; r < 4; ++r) {
        p[nt][r] = exp2f(s[nt][r] - mnew);
        ps += p[nt][r];
      }
    lrun = lrun * alpha + ps;
    mrun = mnew;
    // P -> PV B-frag (keys quad*8 + nt*4 + r = slot k=quad*8+j, j=nt*4+r)
    fragh pf;
    pf.i4[0] = pkh(p[0][0], p[0][1]);
    pf.i4[1] = pkh(p[0][2], p[0][3]);
    pf.i4[2] = pkh(p[1][0], p[1][1]);
    pf.i4[3] = pkh(p[1][2], p[1][3]);
    // rescale O, PV
#pragma unroll
    for (int mt = 0; mt < 4; ++mt) {
#pragma unroll
      for (int r = 0; r < 4; ++r) o[mt][r] *= alpha;
      o[mt] = __builtin_amdgcn_mfma_f32_16x16x32_f16(va[mt].h8, pf.h8, o[mt], 0, 0, 0);
    }
  }

  // wave totals: l across quads (m already common across quads)
  float lw = lrun;
  lw += __shfl_xor(lw, 16);
  lw += __shfl_xor(lw, 32);
  if (lane < 16) {
    sm.M[wid][la] = mrun;
    sm.L[wid][la] = lw;
  }
#pragma unroll
  for (int mt = 0; mt < 4; ++mt)
#pragma unroll
    for (int r = 0; r < 4; ++r)
      sm.O[wid][la][mt * 16 + quad * 4 + r] = o[mt][r];
  __syncthreads();

  // cross-wave split-K combine (weights in exp2 domain)
#pragma unroll
  for (int t = 0; t < 4; ++t) {
    int oidx = t * 256 + tid;  // 1024 outputs: 16 q x 64 m
    int m = oidx >> 4;
    int q = oidx & 15;
    float m0 = fmaxf(fmaxf(sm.M[0][q], sm.M[1][q]), fmaxf(sm.M[2][q], sm.M[3][q]));
    float num = 0.f, den = 0.f;
#pragma unroll
    for (int w = 0; w < 4; ++w) {
      float wgt = exp2f(sm.M[w][q] - m0);
      num += wgt * sm.O[w][q][m];
      den += wgt * sm.L[w][q];
    }
    fout[((size_t)b * 64 + m) * N_ + qbase + q] = num / den;
  }
}

// ---------------- f_up conv (K=64, O=512): SGEMM tiling (validated round 6) --------
__global__ __launch_bounds__(256) void convup_k(const float* __restrict__ fout,
                                                const float* __restrict__ wu,
                                                float* __restrict__ u,
                                                float* __restrict__ stats) {
  const int t = threadIdx.x;
  const int slice = blockIdx.x;
  const int b = slice >> 5;
  const int n0 = (slice & 31) * 128;
  const int o0 = blockIdx.y * 64;

  __shared__ float sA[32][132];
  __shared__ float sW[32][72];

  const int to = (t >> 5) * 8;
  const int tn = (t & 31) * 4;
  float acc[8][4];
#pragma unroll
  for (int i = 0; i < 8; ++i)
#pragma unroll
    for (int j = 0; j < 4; ++j) acc[i][j] = 0.f;

  const float* Ab = fout + (size_t)b * 64 * N_ + n0;
#pragma unroll 1
  for (int k0 = 0; k0 < 64; k0 += 32) {
    __syncthreads();
#pragma unroll
    for (int i = 0; i < 4; ++i) {
      int row = i * 8 + (t >> 5);
      float4 v = *(const float4*)&Ab[(size_t)(k0 + row) * N_ + tn];
      *(float4*)&sA[row][tn] = v;
    }
    {
      int o = t >> 2, kk = (t & 3) * 8;
      float4 w0 = *(const float4*)&wu[(size_t)(o0 + o) * 64 + k0 + kk];
      float4 w1 = *(const float4*)&wu[(size_t)(o0 + o) * 64 + k0 + kk + 4];
      sW[kk + 0][o] = w0.x; sW[kk + 1][o] = w0.y;
      sW[kk + 2][o] = w0.z; sW[kk + 3][o] = w0.w;
      sW[kk + 4][o] = w1.x; sW[kk + 5][o] = w1.y;
      sW[kk + 6][o] = w1.z; sW[kk + 7][o] = w1.w;
    }
    __syncthreads();
#pragma unroll
    for (int k = 0; k < 32; ++k) {
      float4 a = *(const float4*)&sA[k][tn];
      float4 w0 = *(const float4*)&sW[k][to];
      float4 w1 = *(const float4*)&sW[k][to + 4];
      float wv[8] = {w0.x, w0.y, w0.z, w0.w, w1.x, w1.y, w1.z, w1.w};
      float av[4] = {a.x, a.y, a.z, a.w};
#pragma unroll
      for (int i = 0; i < 8; ++i)
#pragma unroll
        for (int j = 0; j < 4; ++j) acc[i][j] += wv[i] * av[j];
    }
  }
  float* Cb = u + ((size_t)b * 512 + o0) * N_ + n0;
#pragma unroll
  for (int i = 0; i < 8; ++i) {
    float4 v = {acc[i][0], acc[i][1], acc[i][2], acc[i][3]};
    *(float4*)&Cb[(size_t)(to + i) * N_ + tn] = v;
  }
#pragma unroll
  for (int i = 0; i < 8; ++i) {
    float s = acc[i][0] + acc[i][1] + acc[i][2] + acc[i][3];
    float q = acc[i][0] * acc[i][0] + acc[i][1] * acc[i][1] +
              acc[i][2] * acc[i][2] + acc[i][3] * acc[i][3];
#pragma unroll
    for (int d = 1; d < 32; d <<= 1) { s += __shfl_xor(s, d); q += __shfl_xor(q, d); }
    if ((t & 31) == 0) {
      atomicAdd(&stats[768 + o0 + to + i], s);
      atomicAdd(&stats[1280 + o0 + to + i], q);
    }
  }
}

// ---------------- residual + final BN ----------------------------------------------
__global__ __launch_bounds__(256) void final_k(const float* __restrict__ x,
                                               const float* __restrict__ u,
                                               const float* __restrict__ gu,
                                               const float* __restrict__ bu,
                                               const float* __restrict__ stats,
                                               float* __restrict__ out) {
  size_t idx = (size_t)blockIdx.x * 256 + threadIdx.x;
  int c = (int)((idx >> 12) & 511);
  float mean = stats[768 + c] * (1.f / CNT);
  float var = stats[1280 + c] * (1.f / CNT) - mean * mean;
  float r = rsqrtf(var + 1e-5f);
  float s = gu[c] * r;
  float sh = bu[c] - mean * s;
  out[idx] = x[idx] + u[idx] * s + sh;
}

extern "C" void kernel_launch(void* const* d_in, const int* in_sizes, int n_in,
                              void* d_out, int out_size, void* d_ws, size_t ws_size,
                              hipStream_t stream) {
  const float* x = (const float*)d_in[0];
  const float* y = (const float*)d_in[1];
  const float* ws1 = (const float*)d_in[2];
  const float* gs1 = (const float*)d_in[3];
  const float* bs1 = (const float*)d_in[4];
  const float* ws2 = (const float*)d_in[5];
  const float* gs2 = (const float*)d_in[6];
  const float* bs2 = (const float*)d_in[7];
  const float* wx1 = (const float*)d_in[8];
  const float* gx1 = (const float*)d_in[9];
  const float* bx1 = (const float*)d_in[10];
  const float* wx2 = (const float*)d_in[11];
  const float* gx2 = (const float*)d_in[12];
  const float* bx2 = (const float*)d_in[13];
  const float* wy1 = (const float*)d_in[14];
  const float* gy1 = (const float*)d_in[15];
  const float* by1 = (const float*)d_in[16];
  const float* wy2 = (const float*)d_in[17];
  const float* gy2 = (const float*)d_in[18];
  const float* by2 = (const float*)d_in[19];
  const float* wu = (const float*)d_in[20];
  const float* gu = (const float*)d_in[21];
  const float* bu = (const float*)d_in[22];
  float* out = (float*)d_out;

  float* w = (float*)d_ws;
  const size_t M1 = 1048576;
  float* z1s = w + 0 * M1;
  float* z1x = w + 1 * M1;
  float* z1y = w + 2 * M1;
  float* z2s = w + 3 * M1;
  float* z2x = w + 4 * M1;
  float* z2y = w + 5 * M1;
  float* fout = w + 6 * M1;
  float* u = w + 7 * M1;  // [4][512][4096] = 8 M floats
  int* Qh = (int*)(w + 15 * M1);
  int* Kh = Qh + 524288;
  int* Vp = Kh + 524288;
  float* stats = (float*)(Vp + 524288);

  hipMemsetAsync(stats, 0, 1792 * sizeof(float), stream);

  conv1_k<<<dim3(128, 3), dim3(256), 0, stream>>>(x, y, ws1, wx1, wy1, z1s, z1x,
                                                  z1y, stats);
  conv2_k<<<dim3(128, 3), dim3(256), 0, stream>>>(
      z1s, z1x, z1y, ws2, wx2, wy2, gs1, bs1, gx1, bx1, gy1, by1, z2s, z2x, z2y,
      stats);
  packQ_k<<<dim3(2048), dim3(256), 0, stream>>>(z2x, gx2, bx2, Qh, stats);
  packK_k<<<dim3(64, 4), dim3(256), 0, stream>>>(z2y, gy2, by2, Kh, stats);
  packV_k<<<dim3(2048), dim3(256), 0, stream>>>(z2s, gs2, bs2, Vp, stats);
  attn_k<<<dim3(1024), dim3(256), 0, stream>>>(Qh, Kh, Vp, fout);
  convup_k<<<dim3(128, 8), dim3(256), 0, stream>>>(fout, wu, u, stats);
  final_k<<<dim3(32768), dim3(256), 0, stream>>>(x, u, gu, bu, stats, out);
}